// Round 1
// baseline (92778.741 us; speedup 1.0000x reference)
//
#include <hip/hip_runtime.h>

#define NN 16384
#define KP1 17
#define EE (NN*16)
#define FMAXV 3.402823466e+38f

// ---------------- h = pos @ W_in + b ----------------
__global__ __launch_bounds__(256) void k_lin_in(const float* __restrict__ pos,
    const float* __restrict__ W, const float* __restrict__ b, float* __restrict__ h) {
  const int t = blockIdx.x*256 + threadIdx.x;   // over N*64
  const int n = t >> 6, c = t & 63;
  float acc = b[c];
  #pragma unroll
  for (int k = 0; k < 11; ++k) acc = fmaf(pos[n*11+k], W[k*64+c], acc);
  h[t] = acc;
}

// ---------------- sq[n] = ||h[n]||^2 ----------------
__global__ __launch_bounds__(256) void k_sqnorm(const float* __restrict__ h, float* __restrict__ sq) {
  const int n = blockIdx.x*256 + threadIdx.x;
  const float4* row = (const float4*)(h + (size_t)n*64);
  float s = 0.f;
  #pragma unroll
  for (int q = 0; q < 16; ++q) { const float4 v = row[q]; s += v.x*v.x + v.y*v.y + v.z*v.z + v.w*v.w; }
  sq[n] = s;
}

// ---------------- fused Gram + top-17 ----------------
// block = 256 threads = 32 rows x 8 col-sub-slices; grid = N/32 = 512
__global__ __launch_bounds__(256) void k_knn(const float* __restrict__ h,
    const float* __restrict__ sq, int* __restrict__ idxout) {
  __shared__ __align__(16) float bt[64][68];   // [c][j], pad 68 (reads: broadcast float4)
  __shared__ float sqj[64];
  __shared__ float mval[32][8][KP1];
  __shared__ int   midx[32][8][KP1];
  const int tid = threadIdx.x;
  const int sub = tid & 7;          // column sub-slice
  const int rl  = tid >> 3;         // local row 0..31
  const int r   = blockIdx.x*32 + rl;

  float a[64];                      // own row, registers (all indices compile-time)
  {
    const float4* rowp = (const float4*)(h + (size_t)r*64);
    #pragma unroll
    for (int q = 0; q < 16; ++q) {
      const float4 v = rowp[q];
      a[4*q] = v.x; a[4*q+1] = v.y; a[4*q+2] = v.z; a[4*q+3] = v.w;
    }
  }
  const float sqr = sq[r];

  float val[KP1]; int vidx[KP1];
  #pragma unroll
  for (int p = 0; p < KP1; ++p) { val[p] = FMAXV; vidx[p] = 0; }

  for (int jt = 0; jt < NN/64; ++jt) {
    const int j0 = jt*64;
    // stage 64 cols x 64 dims, transposed
    #pragma unroll
    for (int l = 0; l < 16; ++l) {
      const int t = l*256 + tid;
      const int j = t >> 6, c = t & 63;
      bt[c][j] = h[(size_t)(j0+j)*64 + c];
    }
    if (tid < 64) sqj[tid] = sq[j0 + tid];
    __syncthreads();

    float acc[8];
    #pragma unroll
    for (int q = 0; q < 8; ++q) acc[q] = 0.f;
    #pragma unroll
    for (int c = 0; c < 64; ++c) {
      const float4 b0 = *(const float4*)&bt[c][sub*8];
      const float4 b1 = *(const float4*)&bt[c][sub*8+4];
      const float ac = a[c];
      acc[0] = fmaf(ac, b0.x, acc[0]); acc[1] = fmaf(ac, b0.y, acc[1]);
      acc[2] = fmaf(ac, b0.z, acc[2]); acc[3] = fmaf(ac, b0.w, acc[3]);
      acc[4] = fmaf(ac, b1.x, acc[4]); acc[5] = fmaf(ac, b1.y, acc[5]);
      acc[6] = fmaf(ac, b1.z, acc[6]); acc[7] = fmaf(ac, b1.w, acc[7]);
    }

    // d = sqrt(max(sq_i + sq_j - 2*dot, 0)); keep 17 smallest, ties -> lower index
    #pragma unroll
    for (int q = 0; q < 8; ++q) {
      const int jl = sub*8 + q;
      const float d2 = sqr + sqj[jl] - 2.f*acc[q];
      const float d = sqrtf(fmaxf(d2, 0.f));
      if (d < val[KP1-1]) {           // strict: equal keeps existing (lower index)
        const int jg = j0 + jl;
        #pragma unroll
        for (int p = KP1-1; p > 0; --p) {
          if (val[p-1] > d)      { val[p] = val[p-1]; vidx[p] = vidx[p-1]; }
          else if (val[p] > d)   { val[p] = d;        vidx[p] = jg; }
        }
        if (val[0] > d) { val[0] = d; vidx[0] = jg; }
      }
    }
    __syncthreads();
  }

  // merge 8 sorted partial lists per row (lex (val, idx))
  #pragma unroll
  for (int p = 0; p < KP1; ++p) { mval[rl][sub][p] = val[p]; midx[rl][sub][p] = vidx[p]; }
  __syncthreads();
  if (sub == 0) {
    int hh0=0,hh1=0,hh2=0,hh3=0,hh4=0,hh5=0,hh6=0,hh7=0;
    for (int p = 0; p < KP1; ++p) {
      float bv = FMAXV; int bi = 0x7fffffff; int bs = -1;
      #define MCAND(S, HS) { if (HS < KP1) { const float v = mval[rl][S][HS]; const int ix = midx[rl][S][HS]; \
          if (v < bv || (v == bv && ix < bi)) { bv = v; bi = ix; bs = S; } } }
      MCAND(0, hh0) MCAND(1, hh1) MCAND(2, hh2) MCAND(3, hh3)
      MCAND(4, hh4) MCAND(5, hh5) MCAND(6, hh6) MCAND(7, hh7)
      #undef MCAND
      idxout[r*KP1 + p] = bi;
      hh0 += (bs==0); hh1 += (bs==1); hh2 += (bs==2); hh3 += (bs==3);
      hh4 += (bs==4); hh5 += (bs==5); hh6 += (bs==6); hh7 += (bs==7);
    }
  }
}

// ---------------- column stats (sum, sumsq) ----------------
__global__ __launch_bounds__(256) void k_colstats(const float* __restrict__ x, const int rows,
    float* __restrict__ s, float* __restrict__ s2) {
  __shared__ float ls[4][64], ls2[4][64];
  const int tid = threadIdx.x;
  const int c = tid & 63, g = tid >> 6;
  float a = 0.f, b = 0.f;
  for (int r = blockIdx.x*4 + g; r < rows; r += 1024) {
    const float v = x[(size_t)r*64 + c];
    a += v; b = fmaf(v, v, b);
  }
  ls[g][c] = a; ls2[g][c] = b;
  __syncthreads();
  if (tid < 64) {
    atomicAdd(&s[tid],  ls[0][tid]+ls[1][tid]+ls[2][tid]+ls[3][tid]);
    atomicAdd(&s2[tid], ls2[0][tid]+ls2[1][tid]+ls2[2][tid]+ls2[3][tid]);
  }
}

// 64-col FMA against LDS weight row (broadcast reads)
__device__ __forceinline__ void fmarow(float (&acc)[64], const float (*ws)[64], int kk, float xv) {
  #pragma unroll
  for (int cq = 0; cq < 16; ++cq) {
    const float4 w4 = *(const float4*)&ws[kk][cq*4];
    acc[cq*4]   = fmaf(xv, w4.x, acc[cq*4]);
    acc[cq*4+1] = fmaf(xv, w4.y, acc[cq*4+1]);
    acc[cq*4+2] = fmaf(xv, w4.z, acc[cq*4+2]);
    acc[cq*4+3] = fmaf(xv, w4.w, acc[cq*4+3]);
  }
}

// ---------------- msg linear-1: y = [h[to] | h[frm]] @ W1 + b1 ----------------
__global__ __launch_bounds__(256) void k_mlpA_gather(const float* __restrict__ h,
    const int* __restrict__ idx, const float* __restrict__ W1, const float* __restrict__ b1,
    float* __restrict__ y) {
  __shared__ __align__(16) float ws[128][64];
  const int tid = threadIdx.x;
  for (int t = tid; t < 128*64/4; t += 256) ((float4*)ws)[t] = ((const float4*)W1)[t];
  __syncthreads();
  const int e = blockIdx.x*256 + tid;
  const int i = e & (NN-1);
  const int k = e >> 14;
  const int to = idx[i*KP1 + k + 1];
  const int fr = idx[i*KP1];
  float acc[64];
  #pragma unroll
  for (int c = 0; c < 64; ++c) acc[c] = b1[c];
  const float4* xa = (const float4*)(h + (size_t)to*64);
  #pragma unroll 2
  for (int kb = 0; kb < 16; ++kb) {
    const float4 x4 = xa[kb];
    fmarow(acc, ws, kb*4,   x4.x); fmarow(acc, ws, kb*4+1, x4.y);
    fmarow(acc, ws, kb*4+2, x4.z); fmarow(acc, ws, kb*4+3, x4.w);
  }
  const float4* xb = (const float4*)(h + (size_t)fr*64);
  #pragma unroll 2
  for (int kb = 0; kb < 16; ++kb) {
    const float4 x4 = xb[kb];
    fmarow(acc, ws, 64+kb*4,   x4.x); fmarow(acc, ws, 64+kb*4+1, x4.y);
    fmarow(acc, ws, 64+kb*4+2, x4.z); fmarow(acc, ws, 64+kb*4+3, x4.w);
  }
  float4* yo = (float4*)(y + (size_t)e*64);
  #pragma unroll
  for (int q = 0; q < 16; ++q) yo[q] = make_float4(acc[4*q], acc[4*q+1], acc[4*q+2], acc[4*q+3]);
}

// ---------------- upd linear-1: y = [h | agg] @ W1 + b1 ----------------
__global__ __launch_bounds__(256) void k_mlpA_cat(const float* __restrict__ h,
    const float* __restrict__ agg, const float* __restrict__ W1, const float* __restrict__ b1,
    float* __restrict__ y) {
  __shared__ __align__(16) float ws[128][64];
  const int tid = threadIdx.x;
  for (int t = tid; t < 128*64/4; t += 256) ((float4*)ws)[t] = ((const float4*)W1)[t];
  __syncthreads();
  const int n = blockIdx.x*256 + tid;
  float acc[64];
  #pragma unroll
  for (int c = 0; c < 64; ++c) acc[c] = b1[c];
  const float4* xa = (const float4*)(h + (size_t)n*64);
  #pragma unroll 2
  for (int kb = 0; kb < 16; ++kb) {
    const float4 x4 = xa[kb];
    fmarow(acc, ws, kb*4,   x4.x); fmarow(acc, ws, kb*4+1, x4.y);
    fmarow(acc, ws, kb*4+2, x4.z); fmarow(acc, ws, kb*4+3, x4.w);
  }
  const float4* xb = (const float4*)(agg + (size_t)n*64);
  #pragma unroll 2
  for (int kb = 0; kb < 16; ++kb) {
    const float4 x4 = xb[kb];
    fmarow(acc, ws, 64+kb*4,   x4.x); fmarow(acc, ws, 64+kb*4+1, x4.y);
    fmarow(acc, ws, 64+kb*4+2, x4.z); fmarow(acc, ws, 64+kb*4+3, x4.w);
  }
  float4* yo = (float4*)(y + (size_t)n*64);
  #pragma unroll
  for (int q = 0; q < 16; ++q) yo[q] = make_float4(acc[4*q], acc[4*q+1], acc[4*q+2], acc[4*q+3]);
}

// ---------------- linear-2 with fused BN+ReLU on input, IN-PLACE on y ----------------
__global__ __launch_bounds__(256) void k_mlpB(float* __restrict__ y,
    const float* __restrict__ s, const float* __restrict__ s2,
    const float* __restrict__ g, const float* __restrict__ be,
    const float* __restrict__ W2, const float* __restrict__ b2, const float invR) {
  __shared__ __align__(16) float ws[64][64];
  __shared__ float sc[64], sh[64];
  const int tid = threadIdx.x;
  for (int t = tid; t < 64*64/4; t += 256) ((float4*)ws)[t] = ((const float4*)W2)[t];
  if (tid < 64) {
    const float m = s[tid]*invR;
    const float v = fmaxf(s2[tid]*invR - m*m, 0.f);
    const float scv = g[tid]*rsqrtf(v + 1e-5f);
    sc[tid] = scv; sh[tid] = be[tid] - m*scv;
  }
  __syncthreads();
  const int e = blockIdx.x*256 + tid;
  float acc[64];
  #pragma unroll
  for (int c = 0; c < 64; ++c) acc[c] = b2[c];
  const float4* yr = (const float4*)(y + (size_t)e*64);
  #pragma unroll 2
  for (int kb = 0; kb < 16; ++kb) {
    const float4 x4 = yr[kb];
    const int k0 = kb*4;
    fmarow(acc, ws, k0,   fmaxf(fmaf(x4.x, sc[k0],   sh[k0]),   0.f));
    fmarow(acc, ws, k0+1, fmaxf(fmaf(x4.y, sc[k0+1], sh[k0+1]), 0.f));
    fmarow(acc, ws, k0+2, fmaxf(fmaf(x4.z, sc[k0+2], sh[k0+2]), 0.f));
    fmarow(acc, ws, k0+3, fmaxf(fmaf(x4.w, sc[k0+3], sh[k0+3]), 0.f));
  }
  float4* yo = (float4*)(y + (size_t)e*64);
  #pragma unroll
  for (int q = 0; q < 16; ++q) yo[q] = make_float4(acc[4*q], acc[4*q+1], acc[4*q+2], acc[4*q+3]);
}

// ---------------- msg final BN+ReLU + scatter-add ----------------
__global__ __launch_bounds__(256) void k_msgC(const float* __restrict__ y,
    const float* __restrict__ s, const float* __restrict__ s2,
    const float* __restrict__ g, const float* __restrict__ be,
    const int* __restrict__ idx, float* __restrict__ agg, const float invR) {
  __shared__ float sc[64], sh[64];
  const int tid = threadIdx.x;
  if (tid < 64) {
    const float m = s[tid]*invR;
    const float v = fmaxf(s2[tid]*invR - m*m, 0.f);
    const float scv = g[tid]*rsqrtf(v + 1e-5f);
    sc[tid] = scv; sh[tid] = be[tid] - m*scv;
  }
  __syncthreads();
  const int t = blockIdx.x*256 + tid;    // over E*64
  const int e = t >> 6, c = t & 63;
  const int i = e & (NN-1), k = e >> 14;
  const int to = idx[i*KP1 + k + 1];
  const float v = fmaxf(fmaf(y[t], sc[c], sh[c]), 0.f);
  atomicAdd(&agg[(size_t)to*64 + c], v);
}

// ---------------- upd final BN+ReLU + residual ----------------
__global__ __launch_bounds__(256) void k_updC(const float* __restrict__ y,
    const float* __restrict__ s, const float* __restrict__ s2,
    const float* __restrict__ g, const float* __restrict__ be,
    float* __restrict__ h, const float invR) {
  __shared__ float sc[64], sh[64];
  const int tid = threadIdx.x;
  if (tid < 64) {
    const float m = s[tid]*invR;
    const float v = fmaxf(s2[tid]*invR - m*m, 0.f);
    const float scv = g[tid]*rsqrtf(v + 1e-5f);
    sc[tid] = scv; sh[tid] = be[tid] - m*scv;
  }
  __syncthreads();
  const int t = blockIdx.x*256 + tid;    // over N*64
  const int c = t & 63;
  h[t] += fmaxf(fmaf(y[t], sc[c], sh[c]), 0.f);
}

// ---------------- out = mean(h) @ predW + predb ----------------
__global__ void k_final(const float* __restrict__ hsum, const float* __restrict__ pW,
                        const float* __restrict__ pb, float* __restrict__ out) {
  const int c = threadIdx.x;   // 64
  float v = hsum[c] * (1.f/(float)NN) * pW[c];
  #pragma unroll
  for (int m = 32; m >= 1; m >>= 1) v += __shfl_xor(v, m, 64);
  if (c == 0) out[0] = v + pb[0];
}

extern "C" void kernel_launch(void* const* d_in, const int* in_sizes, int n_in,
                              void* d_out, int out_size, void* d_ws, size_t ws_size,
                              hipStream_t stream) {
  const float* pos   = (const float*)d_in[0];
  const float* linW  = (const float*)d_in[1];
  const float* linb  = (const float*)d_in[2];
  const float* predW = (const float*)d_in[3];
  const float* predb = (const float*)d_in[4];
  const float* mW1 = (const float*)d_in[5];
  const float* mb1 = (const float*)d_in[6];
  const float* mg1 = (const float*)d_in[7];
  const float* mbe1= (const float*)d_in[8];
  const float* mW2 = (const float*)d_in[9];
  const float* mb2 = (const float*)d_in[10];
  const float* mg2 = (const float*)d_in[11];
  const float* mbe2= (const float*)d_in[12];
  const float* uW1 = (const float*)d_in[13];
  const float* ub1 = (const float*)d_in[14];
  const float* ug1 = (const float*)d_in[15];
  const float* ube1= (const float*)d_in[16];
  const float* uW2 = (const float*)d_in[17];
  const float* ub2 = (const float*)d_in[18];
  const float* ug2 = (const float*)d_in[19];
  const float* ube2= (const float*)d_in[20];

  // workspace layout (~81 MB)
  float* h     = (float*)d_ws;                    // N*64
  float* sq    = h + (size_t)NN*64;               // N
  float* agg   = sq + NN;                         // N*64
  float* ubuf  = agg + (size_t)NN*64;             // N*64
  float* stats = ubuf + (size_t)NN*64;            // 640: 8x64 stat slots + 2x64 pool
  int*   idx   = (int*)(stats + 640);             // N*17
  float* yb    = (float*)(idx + (size_t)NN*KP1);  // E*64

  k_lin_in<<<NN*64/256, 256, 0, stream>>>(pos, linW, linb, h);
  for (int l = 0; l < 4; ++l) {
    k_sqnorm<<<NN/256, 256, 0, stream>>>(h, sq);
    k_knn<<<NN/32, 256, 0, stream>>>(h, sq, idx);
    hipMemsetAsync(stats, 0, 640*sizeof(float), stream);
    hipMemsetAsync(agg, 0, (size_t)NN*64*sizeof(float), stream);
    // msg MLP over E edges
    k_mlpA_gather<<<EE/256, 256, 0, stream>>>(h, idx, mW1 + l*8192, mb1 + l*64, yb);
    k_colstats<<<256, 256, 0, stream>>>(yb, EE, stats, stats+64);
    k_mlpB<<<EE/256, 256, 0, stream>>>(yb, stats, stats+64, mg1 + l*64, mbe1 + l*64,
                                       mW2 + l*4096, mb2 + l*64, 1.f/(float)EE);
    k_colstats<<<256, 256, 0, stream>>>(yb, EE, stats+128, stats+192);
    k_msgC<<<EE*64/256, 256, 0, stream>>>(yb, stats+128, stats+192, mg2 + l*64, mbe2 + l*64,
                                          idx, agg, 1.f/(float)EE);
    // upd MLP over N nodes
    k_mlpA_cat<<<NN/256, 256, 0, stream>>>(h, agg, uW1 + l*8192, ub1 + l*64, ubuf);
    k_colstats<<<256, 256, 0, stream>>>(ubuf, NN, stats+256, stats+320);
    k_mlpB<<<NN/256, 256, 0, stream>>>(ubuf, stats+256, stats+320, ug1 + l*64, ube1 + l*64,
                                       uW2 + l*4096, ub2 + l*64, 1.f/(float)NN);
    k_colstats<<<256, 256, 0, stream>>>(ubuf, NN, stats+384, stats+448);
    k_updC<<<NN*64/256, 256, 0, stream>>>(ubuf, stats+384, stats+448, ug2 + l*64, ube2 + l*64,
                                          h, 1.f/(float)NN);
  }
  hipMemsetAsync(stats+512, 0, 128*sizeof(float), stream);
  k_colstats<<<256, 256, 0, stream>>>(h, NN, stats+512, stats+576);
  k_final<<<1, 64, 0, stream>>>(stats+512, predW, predb, (float*)d_out);
}